// Round 1
// baseline (594.098 us; speedup 1.0000x reference)
//
#include <hip/hip_runtime.h>
#include <hip/hip_bf16.h>

// ContrastiveLoss on MI355X.
// loss = -mean_i (1/P_i) * sum_{j: y_ij=1} [ s_ij - log(exp(s_ij) + nl_i) ]
//   s_ij = 20 * cos(x_i, x_j), nl_i = sum_j (1-y_ij) exp(s_ij)
// One pass over S using log(exp(s)+nl) ~= log nl + e/nl - e^2/(2 nl^2) for
// off-diagonal positives (max e/nl ~ 0.5 -> residual ~1e-4 on loss ~10.5),
// diagonal handled exactly via stored s_ii.

#define NN 8192
#define DD 128

typedef short bf16x8 __attribute__((ext_vector_type(8)));
typedef float f32x4 __attribute__((ext_vector_type(4)));

__device__ inline unsigned short f32_to_bf16_rne(float f) {
    unsigned u = __float_as_uint(f);
    unsigned r = 0x7FFFu + ((u >> 16) & 1u);
    return (unsigned short)((u + r) >> 16);
}

// ---- kernel 1: L2-normalize rows, cast to bf16 ----
__global__ void norm_cast_kernel(const float* __restrict__ x,
                                 unsigned short* __restrict__ xn) {
    const int row = blockIdx.x;
    const int l = threadIdx.x;  // 64 lanes, one wave
    float2 v = reinterpret_cast<const float2*>(x)[row * 64 + l];
    float ss = v.x * v.x + v.y * v.y;
#pragma unroll
    for (int m = 1; m < 64; m <<= 1) ss += __shfl_xor(ss, m);
    float rn = 1.0f / sqrtf(ss);
    ushort2 st;
    st.x = f32_to_bf16_rne(v.x * rn);
    st.y = f32_to_bf16_rne(v.y * rn);
    reinterpret_cast<ushort2*>(xn)[row * 64 + l] = st;
}

// ---- kernel 2: fused S-tile MFMA + exp + y-weighted row accumulation ----
__global__ __launch_bounds__(256) void contrast_main_kernel(
    const unsigned short* __restrict__ xn, const float* __restrict__ y,
    float* __restrict__ nl, float* __restrict__ Aa, float* __restrict__ E1,
    float* __restrict__ E2, float* __restrict__ Pp, float* __restrict__ sdg) {
    __shared__ __align__(1024) char lds[65536];  // A tile 32KB | B tile 32KB

    const int cb = blockIdx.x, rb = blockIdx.y;
    const int t = threadIdx.x;
    const int w = t >> 6, l = t & 63;
    const int wr = w >> 1, wc = w & 1;
    const int lm16 = l & 15, lh = l >> 4;

    // ---- stage A (rows of rb block) and B (rows of cb block), 32KB each.
    // Linear LDS dest (global_load_lds requirement) + inverse-swizzled global
    // source; reads below apply the same XOR involution (byte ^ ((row&7)<<4)).
    {
        const int rh = w >> 1;  // 0 -> A tile, 1 -> B tile
        const int q = w & 1;    // which 16KB half of the tile
        const char* gsrc = reinterpret_cast<const char*>(xn) +
                           (size_t)(rh ? cb : rb) * 32768;
#pragma unroll
        for (int i = 0; i < 16; ++i) {
            int p = q * 16384 + i * 1024 + l * 16;  // byte offset in tile
            int src = p ^ (((p >> 8) & 7) << 4);
            __builtin_amdgcn_global_load_lds(
                (const __attribute__((address_space(1))) void*)(gsrc + src),
                (__attribute__((address_space(3))) void*)(lds + rh * 32768 +
                                                         q * 16384 + i * 1024),
                16, 0, 0);
        }
    }
    asm volatile("s_waitcnt vmcnt(0)" ::: "memory");
    __syncthreads();

    // ---- MFMA: 128x128 tile, K=128. 2x2 waves, 4x4 fragments of 16x16x32.
    f32x4 acc[4][4];
#pragma unroll
    for (int i = 0; i < 4; ++i)
#pragma unroll
        for (int j = 0; j < 4; ++j) {
            f32x4 z = {0.0f, 0.0f, 0.0f, 0.0f};
            acc[i][j] = z;
        }

#pragma unroll
    for (int ks = 0; ks < 4; ++ks) {
        bf16x8 af[4], bfr[4];
#pragma unroll
        for (int mr = 0; mr < 4; ++mr) {
            int r = wr * 64 + mr * 16 + lm16;
            int v = r * 256 + ks * 64 + lh * 16;
            int ph = v ^ ((r & 7) << 4);
            af[mr] = *reinterpret_cast<const bf16x8*>(lds + ph);
        }
#pragma unroll
        for (int nc = 0; nc < 4; ++nc) {
            int c = wc * 64 + nc * 16 + lm16;
            int v = c * 256 + ks * 64 + lh * 16;
            int ph = v ^ ((c & 7) << 4);
            bfr[nc] = *reinterpret_cast<const bf16x8*>(lds + 32768 + ph);
        }
#pragma unroll
        for (int mr = 0; mr < 4; ++mr)
#pragma unroll
            for (int nc = 0; nc < 4; ++nc)
                acc[mr][nc] = __builtin_amdgcn_mfma_f32_16x16x32_bf16(
                    af[mr], bfr[nc], acc[mr][nc], 0, 0, 0);
    }

    // ---- epilogue: e = exp(20*cos); accumulate per-row partials; reduce
    // across the 16 lanes sharing a row; one atomicAdd set per row per wave.
    const int grb = rb * 128 + wr * 64;
    const int gcb = cb * 128 + wc * 64;
#pragma unroll
    for (int mr = 0; mr < 4; ++mr) {
        float pnl[4] = {0, 0, 0, 0}, pA[4] = {0, 0, 0, 0};
        float pE1[4] = {0, 0, 0, 0}, pE2[4] = {0, 0, 0, 0}, pP[4] = {0, 0, 0, 0};
        const int gr0 = grb + mr * 16 + (lh << 2);
#pragma unroll
        for (int nc = 0; nc < 4; ++nc) {
            const int gc = gcb + nc * 16 + lm16;
            const float* yp = y + (size_t)gr0 * NN + gc;
#pragma unroll
            for (int j = 0; j < 4; ++j) {
                float s = acc[mr][nc][j] * 20.0f;
                float e = __expf(s);
                float yv = yp[(size_t)j * NN];
                int gr = gr0 + j;
                bool dg = (gr == gc);
                float yo = dg ? 0.0f : yv;
                pnl[j] = fmaf(1.0f - yv, e, pnl[j]);
                pA[j] = fmaf(yv, s, pA[j]);
                pE1[j] = fmaf(yo, e, pE1[j]);
                pE2[j] = fmaf(yo * e, e, pE2[j]);
                pP[j] += yv;
                if (dg) sdg[gr] = s;
            }
        }
#pragma unroll
        for (int j = 0; j < 4; ++j) {
#pragma unroll
            for (int m = 1; m < 16; m <<= 1) {
                pnl[j] += __shfl_xor(pnl[j], m);
                pA[j] += __shfl_xor(pA[j], m);
                pE1[j] += __shfl_xor(pE1[j], m);
                pE2[j] += __shfl_xor(pE2[j], m);
                pP[j] += __shfl_xor(pP[j], m);
            }
        }
#pragma unroll
        for (int j = 0; j < 4; ++j) {
            if (lm16 == j) {  // static index into partial arrays (rule #20)
                int gr = gr0 + j;
                atomicAdd(&nl[gr], pnl[j]);
                atomicAdd(&Aa[gr], pA[j]);
                atomicAdd(&E1[gr], pE1[j]);
                atomicAdd(&E2[gr], pE2[j]);
                atomicAdd(&Pp[gr], pP[j]);
            }
        }
    }
}

// ---- kernel 3: per-row loss assembly + mean ----
__global__ void finalize_kernel(const float* __restrict__ nl,
                                const float* __restrict__ Aa,
                                const float* __restrict__ E1,
                                const float* __restrict__ E2,
                                const float* __restrict__ Pp,
                                const float* __restrict__ sdg,
                                float* __restrict__ out) {
    __shared__ float red[1024];
    float local = 0.0f;
    for (int r = threadIdx.x; r < NN; r += 1024) {
        float n = nl[r];
        float ln = logf(n);
        float s = sdg[r];
        float diag = s + log1pf(n * expf(-s));  // exact diagonal term
        float p = Pp[r];
        float lm = (Aa[r] - diag - (p - 1.0f) * ln - E1[r] / n +
                    E2[r] / (2.0f * n * n)) /
                   p;
        local += lm;
    }
    red[threadIdx.x] = local;
    __syncthreads();
    for (int sft = 512; sft > 0; sft >>= 1) {
        if ((int)threadIdx.x < sft) red[threadIdx.x] += red[threadIdx.x + sft];
        __syncthreads();
    }
    if (threadIdx.x == 0) out[0] = -red[0] / (float)NN;
}

extern "C" void kernel_launch(void* const* d_in, const int* in_sizes, int n_in,
                              void* d_out, int out_size, void* d_ws,
                              size_t ws_size, hipStream_t stream) {
    const float* x = (const float*)d_in[0];
    const float* y = (const float*)d_in[1];

    char* ws = (char*)d_ws;
    unsigned short* xn = (unsigned short*)ws;        // 8192*128*2 = 2 MB
    float* nl = (float*)(ws + 2097152);              // 6 x 32KB partial arrays
    float* Aa = nl + NN;
    float* E1 = Aa + NN;
    float* E2 = E1 + NN;
    float* Pp = E2 + NN;
    float* sdg = Pp + NN;

    hipMemsetAsync(nl, 0, 5 * NN * sizeof(float), stream);
    norm_cast_kernel<<<NN, 64, 0, stream>>>(x, xn);
    contrast_main_kernel<<<dim3(64, 64), 256, 0, stream>>>(xn, y, nl, Aa, E1,
                                                           E2, Pp, sdg);
    finalize_kernel<<<1, 1024, 0, stream>>>(nl, Aa, E1, E2, Pp, sdg,
                                            (float*)d_out);
}

// Round 2
// 397.929 us; speedup vs baseline: 1.4930x; 1.4930x over previous
//
#include <hip/hip_runtime.h>
#include <hip/hip_bf16.h>

// ContrastiveLoss on MI355X — round 2.
// loss = -mean_i (1/P_i) * sum_{j: y_ij=1} [ s_ij - log(exp(s_ij) + nl_i) ]
// One pass over S: off-diag positives use log(e+nl) ~= log nl + e/nl - e^2/(2nl^2);
// diagonal exact via stored s_ii. Validated round 1 (absmax 0.0).
//
// R2 changes vs R1 (which was latency-bound: 8.5% HBM, 12% VALU, 2% MFMA):
//  - no LDS staging of A/B: xn is 2 MB, L2-resident; fragment loads from
//    global are line-coalesced (16x64B per instr).
//  - all 64 y loads per lane hoisted into registers BEFORE the MFMA: 16 KB
//    per wave in flight >> Little's-law need, HBM saturates.
//  - global atomics (5.2M, 128-way contention) replaced by per-block LDS
//    combine + coalesced partial stores P[5][64][8192] + parallel reducer.

#define NN 8192

typedef short bf16x8 __attribute__((ext_vector_type(8)));
typedef float f32x4 __attribute__((ext_vector_type(4)));

__device__ inline unsigned short f32_to_bf16_rne(float f) {
    unsigned u = __float_as_uint(f);
    unsigned r = 0x7FFFu + ((u >> 16) & 1u);
    return (unsigned short)((u + r) >> 16);
}

// ---- kernel 1: L2-normalize rows, cast to bf16 ----
__global__ void norm_cast_kernel(const float* __restrict__ x,
                                 unsigned short* __restrict__ xn) {
    const int row = blockIdx.x * 4 + (threadIdx.x >> 6);
    const int l = threadIdx.x & 63;
    float2 v = reinterpret_cast<const float2*>(x)[row * 64 + l];
    float ss = v.x * v.x + v.y * v.y;
#pragma unroll
    for (int m = 1; m < 64; m <<= 1) ss += __shfl_xor(ss, m);
    float rn = 1.0f / sqrtf(ss);
    ushort2 st;
    st.x = f32_to_bf16_rne(v.x * rn);
    st.y = f32_to_bf16_rne(v.y * rn);
    reinterpret_cast<ushort2*>(xn)[row * 64 + l] = st;
}

// ---- kernel 2: fused S-tile MFMA + exp + y-weighted row accumulation ----
__global__ __launch_bounds__(256, 2) void contrast_main_kernel(
    const unsigned short* __restrict__ xn, const float* __restrict__ y,
    float* __restrict__ P, float* __restrict__ sdg) {
    const int cb = blockIdx.x, rb = blockIdx.y;
    const int t = threadIdx.x;
    const int w = t >> 6, l = t & 63;
    const int wr = w >> 1, wc = w & 1;
    const int lm16 = l & 15, lh = l >> 4;

    const int grb = rb * 128 + wr * 64;
    const int gcb = cb * 128 + wc * 64;

    // ---- issue ALL y loads first (64 independent 4B loads/lane, in flight
    // under the fragment loads + MFMA). Static indices only (rule #20).
    float ybuf[64];
#pragma unroll
    for (int mr = 0; mr < 4; ++mr) {
        const int gr0 = grb + mr * 16 + (lh << 2);
#pragma unroll
        for (int nc = 0; nc < 4; ++nc) {
            const int gc = gcb + nc * 16 + lm16;
            const float* yp = y + (size_t)gr0 * NN + gc;
#pragma unroll
            for (int j = 0; j < 4; ++j)
                ybuf[mr * 16 + nc * 4 + j] = yp[(size_t)j * NN];
        }
    }

    // ---- MFMA: fragments straight from global (xn L2-resident).
    f32x4 acc[4][4];
#pragma unroll
    for (int i = 0; i < 4; ++i)
#pragma unroll
        for (int j = 0; j < 4; ++j) {
            f32x4 z = {0.0f, 0.0f, 0.0f, 0.0f};
            acc[i][j] = z;
        }

    const char* xb = reinterpret_cast<const char*>(xn);
#pragma unroll
    for (int ks = 0; ks < 4; ++ks) {
        bf16x8 af[4], bfr[4];
#pragma unroll
        for (int mr = 0; mr < 4; ++mr) {
            const size_t r = (size_t)(grb + mr * 16 + lm16);
            af[mr] = *reinterpret_cast<const bf16x8*>(xb + r * 256 + ks * 64 +
                                                      lh * 16);
        }
#pragma unroll
        for (int nc = 0; nc < 4; ++nc) {
            const size_t c = (size_t)(gcb + nc * 16 + lm16);
            bfr[nc] = *reinterpret_cast<const bf16x8*>(xb + c * 256 + ks * 64 +
                                                       lh * 16);
        }
#pragma unroll
        for (int mr = 0; mr < 4; ++mr)
#pragma unroll
            for (int nc = 0; nc < 4; ++nc)
                acc[mr][nc] = __builtin_amdgcn_mfma_f32_16x16x32_bf16(
                    af[mr], bfr[nc], acc[mr][nc], 0, 0, 0);
    }

    // ---- epilogue: per-row partials {nl, A, E1, E2, P}; 16-lane butterfly;
    // combine the two wc-waves via LDS atomics; coalesced store per block.
    __shared__ float red[128][5];
    for (int i = t; i < 640; i += 256) (&red[0][0])[i] = 0.0f;
    __syncthreads();

#pragma unroll
    for (int mr = 0; mr < 4; ++mr) {
        float pnl[4] = {0, 0, 0, 0}, pA[4] = {0, 0, 0, 0};
        float pE1[4] = {0, 0, 0, 0}, pE2[4] = {0, 0, 0, 0}, pP[4] = {0, 0, 0, 0};
        const int gr0 = grb + mr * 16 + (lh << 2);
#pragma unroll
        for (int nc = 0; nc < 4; ++nc) {
            const int gc = gcb + nc * 16 + lm16;
#pragma unroll
            for (int j = 0; j < 4; ++j) {
                float s = acc[mr][nc][j] * 20.0f;
                float e = __expf(s);
                float yv = ybuf[mr * 16 + nc * 4 + j];
                int gr = gr0 + j;
                bool dg = (gr == gc);
                float yo = dg ? 0.0f : yv;
                pnl[j] = fmaf(1.0f - yv, e, pnl[j]);
                pA[j] = fmaf(yv, s, pA[j]);
                pE1[j] = fmaf(yo, e, pE1[j]);
                pE2[j] = fmaf(yo * e, e, pE2[j]);
                pP[j] += yv;
                if (dg) sdg[gr] = s;
            }
        }
#pragma unroll
        for (int j = 0; j < 4; ++j) {
#pragma unroll
            for (int m = 1; m < 16; m <<= 1) {
                pnl[j] += __shfl_xor(pnl[j], m);
                pA[j] += __shfl_xor(pA[j], m);
                pE1[j] += __shfl_xor(pE1[j], m);
                pE2[j] += __shfl_xor(pE2[j], m);
                pP[j] += __shfl_xor(pP[j], m);
            }
        }
#pragma unroll
        for (int j = 0; j < 4; ++j) {
            if (lm16 == j) {  // static index into partial arrays (rule #20)
                const int rib = wr * 64 + mr * 16 + (lh << 2) + j;
                atomicAdd(&red[rib][0], pnl[j]);
                atomicAdd(&red[rib][1], pA[j]);
                atomicAdd(&red[rib][2], pE1[j]);
                atomicAdd(&red[rib][3], pE2[j]);
                atomicAdd(&red[rib][4], pP[j]);
            }
        }
    }
    __syncthreads();

    if (t < 128) {
        const int gr = rb * 128 + t;
#pragma unroll
        for (int q = 0; q < 5; ++q)
            P[(size_t)(q * 64 + cb) * NN + gr] = red[t][q];
    }
}

// ---- kernel 3: reduce partials over the 64 column-blocks + loss assembly ----
__global__ void finalize_kernel(const float* __restrict__ P,
                                const float* __restrict__ sdg,
                                float* __restrict__ out) {
    const int r = blockIdx.x * 256 + threadIdx.x;
    float n = 0.0f, A = 0.0f, E1 = 0.0f, E2 = 0.0f, Pp = 0.0f;
    for (int sl = 0; sl < 64; ++sl) {
        n += P[(size_t)(0 * 64 + sl) * NN + r];
        A += P[(size_t)(1 * 64 + sl) * NN + r];
        E1 += P[(size_t)(2 * 64 + sl) * NN + r];
        E2 += P[(size_t)(3 * 64 + sl) * NN + r];
        Pp += P[(size_t)(4 * 64 + sl) * NN + r];
    }
    const float s = sdg[r];
    const float ln = logf(n);
    const float diag = s + log1pf(n * expf(-s));  // exact diagonal term
    float lm = (A - diag - (Pp - 1.0f) * ln - E1 / n + E2 / (2.0f * n * n)) / Pp;

    __shared__ float red[256];
    red[threadIdx.x] = lm;
    __syncthreads();
    for (int sft = 128; sft > 0; sft >>= 1) {
        if ((int)threadIdx.x < sft) red[threadIdx.x] += red[threadIdx.x + sft];
        __syncthreads();
    }
    if (threadIdx.x == 0) atomicAdd(out, -red[0] / (float)NN);
}

extern "C" void kernel_launch(void* const* d_in, const int* in_sizes, int n_in,
                              void* d_out, int out_size, void* d_ws,
                              size_t ws_size, hipStream_t stream) {
    const float* x = (const float*)d_in[0];
    const float* y = (const float*)d_in[1];

    char* ws = (char*)d_ws;
    unsigned short* xn = (unsigned short*)ws;      // 8192*128*2 = 2 MB
    float* P = (float*)(ws + (2 << 20));           // [5][64][8192] = 10 MB
    float* sdg = P + 5 * 64 * NN;                  // 32 KB

    hipMemsetAsync(d_out, 0, sizeof(float), stream);
    norm_cast_kernel<<<NN / 4, 256, 0, stream>>>(x, xn);
    contrast_main_kernel<<<dim3(64, 64), 256, 0, stream>>>(xn, y, P, sdg);
    finalize_kernel<<<NN / 256, 256, 0, stream>>>(P, sdg, (float*)d_out);
}